// Round 20
// baseline (222.250 us; speedup 1.0000x reference)
//
#include <hip/hip_runtime.h>
#include <hip/hip_bf16.h>

typedef unsigned short u16;
using f32x4  = __attribute__((ext_vector_type(4))) float;
using bf16x8 = __attribute__((ext_vector_type(8))) short;

#define N_B 4
#define N_S 4096
#define N_C 1280
#define N_DC 2048
#define N_H 20
#define N_D 64

__device__ __forceinline__ u16 f2b(float f) {
  union { float f; unsigned u; } x; x.f = f;
  return (u16)((x.u + 0x7fffu + ((x.u >> 16) & 1u)) >> 16);
}

__device__ __forceinline__ void gld16(const u16* g, u16* l) {
  __builtin_amdgcn_global_load_lds(
      (const __attribute__((address_space(1))) unsigned int*)(g),
      (__attribute__((address_space(3))) unsigned int*)(l), 16, 0, 0);
}

struct TPargs { const float* s[8]; u16* d[8]; int K[8]; };

// 64n x 128k vectorized transpose tile: src f32 (K x N_C) -> dst bf16 (N x K)
__device__ __forceinline__ void tp_tile(const float* __restrict__ src,
                                        u16* __restrict__ dst, int K,
                                        int n0, int k0, int t, char* smem) {
  float (*tl)[65] = (float(*)[65])smem;   // [128][65] = 33280 B
  int r = t >> 4, c4 = (t & 15) * 4;
#pragma unroll
  for (int j = 0; j < 8; j++) {
    float4 v4 = *(const float4*)(src + (size_t)(k0 + j * 16 + r) * N_C + n0 + c4);
    tl[j * 16 + r][c4]     = v4.x;
    tl[j * 16 + r][c4 + 1] = v4.y;
    tl[j * 16 + r][c4 + 2] = v4.z;
    tl[j * 16 + r][c4 + 3] = v4.w;
  }
  __syncthreads();
  int n = t >> 4, koff = (t & 15) * 8;
#pragma unroll
  for (int j = 0; j < 4; j++) {
    int nn = j * 16 + n;
    alignas(16) u16 tmp[8];
#pragma unroll
    for (int kk = 0; kk < 8; kk++) tmp[kk] = f2b(tl[koff + kk][nn]);
    *(uint4*)(dst + (size_t)(n0 + nn) * K + k0 + koff) = *(uint4*)tmp;
  }
}

// ---------- prep A: 7 weight transposes (64x128 tiles) + encoder pack
// blocks [0,2240): transpose; [2240,2580): encpack
__global__ __launch_bounds__(256)
void k_prep(TPargs a, const float* __restrict__ enc, u16* __restrict__ txt,
            u16* __restrict__ img, u16* __restrict__ lbl) {
  __shared__ __align__(16) char smem[33280];
  int bx = blockIdx.x, t = threadIdx.x;
  if (bx < 2240) {
    int z = bx / 320, v = bx % 320;
    int n0 = (v % 20) * 64, k0 = (v / 20) * 128;
    int K = a.K[z];
    if (k0 >= K) return;
    tp_tile(a.s[z], a.d[z], K, n0, k0, t, smem);
  } else {
    int row = bx - 2240;            // 0..339 = b*85 + l
    int b = row / 85, l = row % 85;
    const float* s = enc + (size_t)row * N_DC;
    u16* d;
    if (l < 77)      d = txt + (size_t)(b * 77 + l) * N_DC;
    else if (l < 81) d = img + (size_t)(b * 4 + (l - 77)) * N_DC;
    else             d = lbl + (size_t)(b * 4 + (l - 81)) * N_DC;
    for (int i = t * 8; i < N_DC; i += 256 * 8) {
      const float4 v0 = *(const float4*)(s + i);
      const float4 v1 = *(const float4*)(s + i + 4);
      alignas(16) u16 tmp[8];
      tmp[0] = f2b(v0.x); tmp[1] = f2b(v0.y); tmp[2] = f2b(v0.z); tmp[3] = f2b(v0.w);
      tmp[4] = f2b(v1.x); tmp[5] = f2b(v1.y); tmp[6] = f2b(v1.z); tmp[7] = f2b(v1.w);
      *(uint4*)(d + i) = *(uint4*)tmp;
    }
  }
}

// ---------- prep B: hs f32 -> bf16, lane-dense (16B load / 8B store per lane)
__global__ __launch_bounds__(256)
void k_cvt(const float* __restrict__ src, u16* __restrict__ dst, int n4) {
  for (int i = blockIdx.x * 256 + threadIdx.x; i < n4; i += 2048 * 256) {
    float4 v = ((const float4*)src)[i];
    union { u16 s[4]; uint2 u; } tmp;
    tmp.s[0] = f2b(v.x); tmp.s[1] = f2b(v.y);
    tmp.s[2] = f2b(v.z); tmp.s[3] = f2b(v.w);
    ((uint2*)dst)[i] = tmp.u;
  }
}

// ====== 128x160 GEMM body (r11/r15: straight-line dbuf, 2 blk/CU) ==========
__device__ __forceinline__ void stage32(const u16* __restrict__ g, int ldK,
                                        int row0, int kk, u16* ldsb,
                                        int w, int lane) {
  int r = row0 + w * 8 + (lane >> 3);
  int gslot = ((lane & 7) ^ (lane >> 3)) << 3;
  gld16(g + (size_t)r * ldK + kk + gslot, ldsb + w * 512);
}
__device__ __forceinline__ void stageA(const u16* Ag, int K, int kk, u16* ldsb,
                                       int w, int lane) {
#pragma unroll
  for (int j = 0; j < 4; j++)
    stage32(Ag, K, j * 32, kk, ldsb + j * 2048, w, lane);
}
__device__ __forceinline__ void stageB(const u16* Bg, int K, int kk, u16* ldsb,
                                       int w, int lane) {
#pragma unroll
  for (int j = 0; j < 5; j++)
    stage32(Bg, K, j * 32, kk, ldsb + j * 2048, w, lane);
}

#define RD_A2(aoff, mh)                                                      \
  _Pragma("unroll") for (int mi = 0; mi < 2; mi++) {                         \
    _Pragma("unroll") for (int ks = 0; ks < 2; ks++) {                       \
      int row = wr * 64 + ((mh) * 2 + mi) * 16 + lrow;                       \
      int slot = (ks * 4 + g) ^ (lane & 7);                                  \
      af[mi][ks] = *(const bf16x8*)&lds[(aoff) + row * 64 + slot * 8];       \
    }                                                                        \
  }

#define RD_B5(boff)                                                          \
  _Pragma("unroll") for (int n = 0; n < 5; n++) {                            \
    _Pragma("unroll") for (int ks = 0; ks < 2; ks++) {                       \
      int row = wc * 80 + n * 16 + lrow;                                     \
      int slot = (ks * 4 + g) ^ (lane & 7);                                  \
      bf[n][ks] = *(const bf16x8*)&lds[(boff) + row * 64 + slot * 8];        \
    }                                                                        \
  }

#define MFMA10(mh)                                                           \
  _Pragma("unroll") for (int ks = 0; ks < 2; ks++) {                         \
    _Pragma("unroll") for (int n = 0; n < 5; n++)                            \
      acc[mh][n] = __builtin_amdgcn_mfma_f32_16x16x32_bf16(                  \
          af[(mh) & 1][ks], bf[n][ks], acc[mh][n], 0, 0, 0);                 \
  }

#define BARR()  __builtin_amdgcn_s_barrier()
#define VM0()   asm volatile("s_waitcnt vmcnt(0)" ::: "memory")
#define PRIO(x) __builtin_amdgcn_s_setprio(x)

template<int EPI>
__device__ __forceinline__ void gemm_body(
    const u16* __restrict__ A, const u16* __restrict__ Bt, void* __restrict__ Cv,
    int M, int N, int K, float scale,
    const float* __restrict__ bias, const float* __restrict__ resid,
    u16* lds, int bid, int nwg) {
  const int t = threadIdx.x, lane = t & 63, w = t >> 6;   // w in 0..3
  const int wr = w >> 1, wc = w & 1;
  const int lrow = lane & 15, g = lane >> 4;

  int nt = N / 160;
  int swz = ((nwg & 7) == 0) ? ((bid & 7) * (nwg >> 3) + (bid >> 3)) : bid;
  int bm = swz / nt, bn = swz % nt;

  const u16* Ag = A  + (size_t)bm * 128 * K;
  const u16* Bg = Bt + (size_t)bn * 160 * K;
  const int NT = K >> 6;

  f32x4 acc[4][5] = {};
  bf16x8 af[2][2], bf[5][2];

  stageA(Ag, K, 0, lds + 0,     w, lane);
  stageB(Bg, K, 0, lds + 16384, w, lane);
  VM0();
  BARR();

  for (int tt = 0; tt < NT; ++tt) {
    int c = tt & 1;
    int aof  = c * 8192,        bof  = 16384 + c * 10240;
    int aof1 = (c ^ 1) * 8192,  bof1 = 16384 + (c ^ 1) * 10240;
    if (tt + 1 < NT) {
      stageA(Ag, K, (tt + 1) * 64, lds + aof1, w, lane);
      stageB(Bg, K, (tt + 1) * 64, lds + bof1, w, lane);
    }
    RD_B5(bof);
    RD_A2(aof, 0);
    PRIO(1); MFMA10(0); MFMA10(1); PRIO(0);
    RD_A2(aof, 1);
    PRIO(1); MFMA10(2); MFMA10(3); PRIO(0);
    VM0();
    BARR();
  }

#pragma unroll
  for (int m = 0; m < 4; m++) {
    int row = bm * 128 + wr * 64 + m * 16 + g * 4;
#pragma unroll
    for (int n = 0; n < 5; n++) {
      int col = bn * 160 + wc * 80 + n * 16 + lrow;
#pragma unroll
      for (int j = 0; j < 4; j++) {
        float v = acc[m][n][j];
        if constexpr (EPI == 1)
          ((u16*)Cv)[(size_t)(row + j) * N + col] = f2b(v * scale);
        else
          ((float*)Cv)[(size_t)(row + j) * N + col] =
              v + bias[col] + resid[(size_t)(row + j) * N + col];
      }
    }
  }
}

// ---------- kv-projection body (XOR slot swizzle, conflict-free)
__device__ __forceinline__ void kv_body(
    const u16* __restrict__ A, const u16* __restrict__ Bt, u16* __restrict__ C,
    int M, int bm, int bn, u16* ldsraw) {
  u16 (*lds)[2][8192] = (u16(*)[2][8192])ldsraw;
  const int K = 2048;
  int t = threadIdx.x, lane = t & 63, w = t >> 6;
  int wm = w >> 1, wn = w & 1;
  int gs = ((lane & 7) ^ (lane >> 3)) * 8;
  int rsub = lane >> 3;

  f32x4 acc[4][4] = {};

#define KVSTAGE(kt, buf)                                                      \
  {                                                                           \
    int k0 = (kt) * 64;                                                       \
    _Pragma("unroll") for (int i2 = 0; i2 < 4; i2++) {                        \
      int rloc = w * 32 + i2 * 8;                                             \
      int ra = bm * 128 + rloc + rsub; if (ra >= M) ra = M - 1;               \
      int rb = bn * 128 + rloc + rsub;                                        \
      gld16(A  + (size_t)ra * K + k0 + gs, &lds[buf][0][rloc * 64]);          \
      gld16(Bt + (size_t)rb * K + k0 + gs, &lds[buf][1][rloc * 64]);          \
    }                                                                         \
  }

  KVSTAGE(0, 0);
  VM0();
  __syncthreads();
  int cur = 0;
  for (int kt = 0; kt < 32; kt++) {
    if (kt < 31) KVSTAGE(kt + 1, cur ^ 1);
#pragma unroll
    for (int ks = 0; ks < 2; ks++) {
      bf16x8 afr[4], bfr[4];
#pragma unroll
      for (int m = 0; m < 4; m++) {
        int row = wm * 64 + m * 16 + (lane & 15);
        int slot = (ks * 4 + (lane >> 4)) ^ (lane & 7);
        afr[m] = *(bf16x8*)&lds[cur][0][row * 64 + slot * 8];
      }
#pragma unroll
      for (int n = 0; n < 4; n++) {
        int row = wn * 64 + n * 16 + (lane & 15);
        int slot = (ks * 4 + (lane >> 4)) ^ (lane & 7);
        bfr[n] = *(bf16x8*)&lds[cur][1][row * 64 + slot * 8];
      }
#pragma unroll
      for (int m = 0; m < 4; m++)
#pragma unroll
        for (int n = 0; n < 4; n++)
          acc[m][n] = __builtin_amdgcn_mfma_f32_16x16x32_bf16(afr[m], bfr[n], acc[m][n], 0, 0, 0);
    }
    VM0();
    __syncthreads();
    cur ^= 1;
  }
#undef KVSTAGE

#pragma unroll
  for (int m = 0; m < 4; m++) {
    int row = bm * 128 + wm * 64 + m * 16 + ((lane >> 4) << 2);
#pragma unroll
    for (int n = 0; n < 4; n++) {
      int col = bn * 128 + wn * 64 + n * 16 + (lane & 15);
#pragma unroll
      for (int j = 0; j < 4; j++) {
        int r = row + j;
        if (r >= M) continue;
        C[(size_t)r * 1280 + col] = f2b(acc[m][n][j]);
      }
    }
  }
}

// ---------- combined: 100 KV blocks FIRST (overlap Q round 1), then 1024 Q
__global__ __launch_bounds__(256, 2)
void qkv_gemm(const u16* __restrict__ hsb, const u16* __restrict__ wq,
              u16* __restrict__ qbuf,
              const u16* __restrict__ etxt, const u16* __restrict__ eimg,
              const u16* __restrict__ elbl,
              const u16* __restrict__ wk,   const u16* __restrict__ wv,
              const u16* __restrict__ wkip, const u16* __restrict__ wvip,
              const u16* __restrict__ wklb, const u16* __restrict__ wvlb,
              u16* ktxt, u16* vtxt, u16* kimg, u16* vimg, u16* klbl, u16* vlbl) {
  __shared__ __align__(16) u16 lds[36864];   // 72 KB
  int bx = blockIdx.x;
  if (bx < 100) {
    int bn = bx % 10, my = (bx / 10) % 5, kv = bx / 50;
    const u16 *A, *Bt; u16* C; int M, bm;
    if (my < 3)       { A = etxt; M = 308; bm = my; Bt = kv ? wv   : wk;   C = kv ? vtxt : ktxt; }
    else if (my == 3) { A = eimg; M = 16;  bm = 0;  Bt = kv ? wvip : wkip; C = kv ? vimg : kimg; }
    else              { A = elbl; M = 16;  bm = 0;  Bt = kv ? wvlb : wklb; C = kv ? vlbl : klbl; }
    kv_body(A, Bt, C, M, bm, bn, lds);
  } else {
    gemm_body<1>(hsb, wq, qbuf, 16384, 1280, 1280, 0.125f, nullptr, nullptr,
                 lds, bx - 100, 1024);
  }
}

// ---------- O-proj wrapper
__global__ __launch_bounds__(256, 2)
void gemm_o(const u16* __restrict__ A, const u16* __restrict__ Bt,
            float* __restrict__ Cv, const float* __restrict__ bias,
            const float* __restrict__ resid) {
  __shared__ __align__(16) u16 lds[36864];
  gemm_body<2>(A, Bt, Cv, 16384, 1280, 1280, 1.f, bias, resid,
               lds, blockIdx.x, 1024);
}

// ---------- fused attention + Wo transpose (blocks 2560..2759)
#define QSTR 72
#define PSTR 104

__global__ __launch_bounds__(256, 2)
void attn_kern(const u16* __restrict__ q,
               const u16* __restrict__ ktxt, const u16* __restrict__ vtxt,
               const u16* __restrict__ kimg, const u16* __restrict__ vimg,
               const u16* __restrict__ klbl, const u16* __restrict__ vlbl,
               u16* __restrict__ outa,
               const float* __restrict__ Wo, u16* __restrict__ wo_t) {
  __shared__ __align__(16) char smem[45568];
  int bx = blockIdx.x;
  int t = threadIdx.x;
  if (bx >= 2560) {
    int v = bx - 2560;              // 0..199
    int n0 = (v % 20) * 64, k0 = (v / 20) * 128;
    tp_tile(Wo, wo_t, 1280, n0, k0, t, smem);
    return;
  }
  u16* Qs = (u16*)smem;
  u16* Ks = (u16*)(smem + 18432);
  u16* Ps = (u16*)smem;
  u16* Vt = (u16*)(smem + 32256);

  int st = bx & 31, h = (bx >> 5) % 20, b = bx / 640;
  int lane = t & 63, w = t >> 6;
  int s0 = st * 128;
  int c = lane & 15, g = lane >> 4;

  for (int i = t; i < 27136 / 16; i += 256)
    ((uint4*)(smem + 18432))[i] = make_uint4(0, 0, 0, 0);
#pragma unroll
  for (int i = 0; i < 4; i++) {
    int cid = t + i * 256; int r = cid >> 3, c8 = cid & 7;
    *(uint4*)&Qs[r * QSTR + c8 * 8] =
        *(const uint4*)(q + (size_t)(b * N_S + s0 + r) * N_C + h * N_D + c8 * 8);
  }
  __syncthreads();
  for (int cid = t; cid < 680; cid += 256) {
    int l = cid >> 3, c8 = cid & 7;
    const u16* p;
    if (l < 77)      p = ktxt + (size_t)(b * 77 + l) * N_C + h * N_D + c8 * 8;
    else if (l < 81) p = kimg + (size_t)(b * 4 + l - 77) * N_C + h * N_D + c8 * 8;
    else             p = klbl + (size_t)(b * 4 + l - 81) * N_C + h * N_D + c8 * 8;
    int row = (l < 77) ? l : l + 3;
    *(uint4*)&Ks[row * QSTR + c8 * 8] = *(const uint4*)p;
  }
  for (int e = t; e < 85 * 64; e += 256) {
    int l = e >> 6, d = e & 63;
    const u16* p;
    if (l < 77)      p = vtxt + (size_t)(b * 77 + l) * N_C + h * N_D + d;
    else if (l < 81) p = vimg + (size_t)(b * 4 + l - 77) * N_C + h * N_D + d;
    else             p = vlbl + (size_t)(b * 4 + l - 81) * N_C + h * N_D + d;
    int slot = (l < 77) ? l : l + 3;
    Vt[d * PSTR + slot] = *p;
  }
  __syncthreads();

  f32x4 sacc[2][6] = {};
#pragma unroll
  for (int ks = 0; ks < 2; ks++) {
    bf16x8 aq[2], bk[6];
#pragma unroll
    for (int m = 0; m < 2; m++)
      aq[m] = *(bf16x8*)&Qs[(w * 32 + m * 16 + c) * QSTR + ks * 32 + g * 8];
#pragma unroll
    for (int n = 0; n < 6; n++)
      bk[n] = *(bf16x8*)&Ks[(n * 16 + c) * QSTR + ks * 32 + g * 8];
#pragma unroll
    for (int m = 0; m < 2; m++)
#pragma unroll
      for (int n = 0; n < 6; n++)
        sacc[m][n] = __builtin_amdgcn_mfma_f32_16x16x32_bf16(aq[m], bk[n], sacc[m][n], 0, 0, 0);
  }
  __syncthreads();

  const float NEG = -1e30f;
#pragma unroll
  for (int m = 0; m < 2; m++) {
#pragma unroll
    for (int j = 0; j < 4; j++) {
      float tmax = NEG;
#pragma unroll
      for (int n = 0; n < 5; n++)
        if (n * 16 + c < 77) tmax = fmaxf(tmax, sacc[m][n][j]);
#pragma unroll
      for (int off = 1; off < 16; off <<= 1) tmax = fmaxf(tmax, __shfl_xor(tmax, off));
      float pv[5], tsum = 0.f;
#pragma unroll
      for (int n = 0; n < 5; n++) {
        float v = (n * 16 + c < 77) ? __expf(sacc[m][n][j] - tmax) : 0.f;
        pv[n] = v; tsum += v;
      }
#pragma unroll
      for (int off = 1; off < 16; off <<= 1) tsum += __shfl_xor(tsum, off);
      float v5 = sacc[m][5][j];
      float imax = (c < 4) ? v5 : NEG;
#pragma unroll
      for (int off = 1; off < 16; off <<= 1) imax = fmaxf(imax, __shfl_xor(imax, off));
      float ie = (c < 4) ? __expf(v5 - imax) : 0.f, isum = ie;
#pragma unroll
      for (int off = 1; off < 16; off <<= 1) isum += __shfl_xor(isum, off);
      float lmax = (c >= 4 && c < 8) ? v5 : NEG;
#pragma unroll
      for (int off = 1; off < 16; off <<= 1) lmax = fmaxf(lmax, __shfl_xor(lmax, off));
      float le = (c >= 4 && c < 8) ? __expf(v5 - lmax) : 0.f, lsum = le;
#pragma unroll
      for (int off = 1; off < 16; off <<= 1) lsum += __shfl_xor(lsum, off);

      float rt = 1.f / tsum;
      float p5 = (c < 4) ? ie / isum : ((c < 8) ? le / lsum : 0.f);
      int rowl = w * 32 + m * 16 + g * 4 + j;
#pragma unroll
      for (int n = 0; n < 5; n++)
        Ps[rowl * PSTR + n * 16 + c] = f2b(pv[n] * rt);
      Ps[rowl * PSTR + 80 + c] = f2b(p5);
    }
  }
  __syncthreads();

  f32x4 oacc[2][4] = {};
#pragma unroll
  for (int ks = 0; ks < 3; ks++) {
    bf16x8 ap[2], bv[4];
#pragma unroll
    for (int m = 0; m < 2; m++)
      ap[m] = *(bf16x8*)&Ps[(w * 32 + m * 16 + c) * PSTR + ks * 32 + g * 8];
#pragma unroll
    for (int n = 0; n < 4; n++)
      bv[n] = *(bf16x8*)&Vt[(n * 16 + c) * PSTR + ks * 32 + g * 8];
#pragma unroll
    for (int m = 0; m < 2; m++)
#pragma unroll
      for (int n = 0; n < 4; n++)
        oacc[m][n] = __builtin_amdgcn_mfma_f32_16x16x32_bf16(ap[m], bv[n], oacc[m][n], 0, 0, 0);
  }

#pragma unroll
  for (int m = 0; m < 2; m++) {
    int rbase = w * 32 + m * 16 + g * 4;
#pragma unroll
    for (int n = 0; n < 4; n++) {
      int d = n * 16 + c;
#pragma unroll
      for (int j = 0; j < 4; j++) {
        int s = s0 + rbase + j;
        outa[(size_t)(b * N_S + s) * N_C + h * N_D + d] = f2b(oacc[m][n][j]);
      }
    }
  }
}

extern "C" void kernel_launch(void* const* d_in, const int* in_sizes, int n_in,
                              void* d_out, int out_size, void* d_ws, size_t ws_size,
                              hipStream_t stream) {
  const float* hs   = (const float*)d_in[0];
  const float* enc  = (const float*)d_in[1];
  const float* Wq   = (const float*)d_in[2];
  const float* Wk   = (const float*)d_in[3];
  const float* Wv   = (const float*)d_in[4];
  const float* Wkip = (const float*)d_in[5];
  const float* Wvip = (const float*)d_in[6];
  const float* Wklb = (const float*)d_in[7];
  const float* Wvlb = (const float*)d_in[8];
  const float* Wo   = (const float*)d_in[9];
  const float* bo   = (const float*)d_in[10];

  if (ws_size < 83087360u) return;
  char* ws = (char*)d_ws;
  u16* wq_t   = (u16*)(ws + 0);
  u16* wo_t   = (u16*)(ws + 3276800);
  u16* wk_t   = (u16*)(ws + 6553600);
  u16* wv_t   = (u16*)(ws + 11796480);
  u16* wkip_t = (u16*)(ws + 17039360);
  u16* wvip_t = (u16*)(ws + 22282240);
  u16* wklb_t = (u16*)(ws + 27525120);
  u16* wvlb_t = (u16*)(ws + 32768000);
  u16* etxt   = (u16*)(ws + 38010880);
  u16* eimg   = (u16*)(ws + 39272448);
  u16* elbl   = (u16*)(ws + 39337984);
  u16* ktxt   = (u16*)(ws + 39403520);
  u16* vtxt   = (u16*)(ws + 40192000);
  u16* kimg   = (u16*)(ws + 40980480);
  u16* vimg   = (u16*)(ws + 41021440);
  u16* klbl   = (u16*)(ws + 41062400);
  u16* vlbl   = (u16*)(ws + 41103360);
  u16* attn   = (u16*)(ws + 41144320);
  // d_out (84 MB): lower half = q bf16, upper half = hs bf16; both consumed
  // before the final O-proj overwrites d_out with f32 output.
  u16* qbuf   = (u16*)d_out;
  u16* hsb    = (u16*)d_out + (size_t)N_S * N_B * N_C;

  TPargs tp;   // 7 weights in k_prep; Wo handled inside attn launch
  tp.s[0] = Wq;   tp.d[0] = wq_t;   tp.K[0] = 1280;
  tp.s[1] = Wk;   tp.d[1] = wk_t;   tp.K[1] = 2048;
  tp.s[2] = Wv;   tp.d[2] = wv_t;   tp.K[2] = 2048;
  tp.s[3] = Wkip; tp.d[3] = wkip_t; tp.K[3] = 2048;
  tp.s[4] = Wvip; tp.d[4] = wvip_t; tp.K[4] = 2048;
  tp.s[5] = Wklb; tp.d[5] = wklb_t; tp.K[5] = 2048;
  tp.s[6] = Wvlb; tp.d[6] = wvlb_t; tp.K[6] = 2048;
  tp.s[7] = Wo;   tp.d[7] = wo_t;   tp.K[7] = 1280;   // unused in k_prep

  // prep A: transposes + encoder pack (33 KB LDS blocks only)
  k_prep<<<2580, 256, 0, stream>>>(tp, enc, etxt, eimg, elbl);
  // prep B: hs->bf16, lane-dense, zero LDS, full occupancy; LAST so hsb
  // is L3-warm when qkv_gemm launches
  k_cvt<<<2048, 256, 0, stream>>>(hs, hsb, (N_B * N_S * N_C) / 4);

  // KV blocks first (overlap with Q-proj round 1), then 1024 Q-proj blocks
  qkv_gemm<<<1124, 256, 0, stream>>>(hsb, wq_t, qbuf,
                                     etxt, eimg, elbl,
                                     wk_t, wv_t, wkip_t, wvip_t, wklb_t, wvlb_t,
                                     ktxt, vtxt, kimg, vimg, klbl, vlbl);

  // attention (2560 blocks) + Wo transpose (200 blocks, consumed by gemm_o)
  attn_kern<<<2760, 256, 0, stream>>>(qbuf, ktxt, vtxt, kimg, vimg,
                                      klbl, vlbl, attn, Wo, wo_t);

  // out = attn @ Wo + bo + hs
  gemm_o<<<1024, 256, 0, stream>>>(attn, wo_t, (float*)d_out, bo, hs);
}

// Round 21
// 208.579 us; speedup vs baseline: 1.0655x; 1.0655x over previous
//
#include <hip/hip_runtime.h>
#include <hip/hip_bf16.h>

typedef unsigned short u16;
using f32x4  = __attribute__((ext_vector_type(4))) float;
using bf16x8 = __attribute__((ext_vector_type(8))) short;

#define N_B 4
#define N_S 4096
#define N_C 1280
#define N_DC 2048
#define N_H 20
#define N_D 64

__device__ __forceinline__ u16 f2b(float f) {
  union { float f; unsigned u; } x; x.f = f;
  return (u16)((x.u + 0x7fffu + ((x.u >> 16) & 1u)) >> 16);
}

__device__ __forceinline__ void gld16(const u16* g, u16* l) {
  __builtin_amdgcn_global_load_lds(
      (const __attribute__((address_space(1))) unsigned int*)(g),
      (__attribute__((address_space(3))) unsigned int*)(l), 16, 0, 0);
}

struct TPargs { const float* s[8]; u16* d[8]; int K[8]; };

// 64n x 128k vectorized transpose tile: src f32 (K x N_C) -> dst bf16 (N x K)
__device__ __forceinline__ void tp_tile(const float* __restrict__ src,
                                        u16* __restrict__ dst, int K,
                                        int n0, int k0, int t, char* smem) {
  float (*tl)[65] = (float(*)[65])smem;   // [128][65] = 33280 B
  int r = t >> 4, c4 = (t & 15) * 4;
#pragma unroll
  for (int j = 0; j < 8; j++) {
    float4 v4 = *(const float4*)(src + (size_t)(k0 + j * 16 + r) * N_C + n0 + c4);
    tl[j * 16 + r][c4]     = v4.x;
    tl[j * 16 + r][c4 + 1] = v4.y;
    tl[j * 16 + r][c4 + 2] = v4.z;
    tl[j * 16 + r][c4 + 3] = v4.w;
  }
  __syncthreads();
  int n = t >> 4, koff = (t & 15) * 8;
#pragma unroll
  for (int j = 0; j < 4; j++) {
    int nn = j * 16 + n;
    alignas(16) u16 tmp[8];
#pragma unroll
    for (int kk = 0; kk < 8; kk++) tmp[kk] = f2b(tl[koff + kk][nn]);
    *(uint4*)(dst + (size_t)(n0 + nn) * K + k0 + koff) = *(uint4*)tmp;
  }
}

// ---------- prep A: 7 weight transposes (64x128 tiles) + encoder pack
__global__ __launch_bounds__(256)
void k_prep(TPargs a, const float* __restrict__ enc, u16* __restrict__ txt,
            u16* __restrict__ img, u16* __restrict__ lbl) {
  __shared__ __align__(16) char smem[33280];
  int bx = blockIdx.x, t = threadIdx.x;
  if (bx < 2240) {
    int z = bx / 320, v = bx % 320;
    int n0 = (v % 20) * 64, k0 = (v / 20) * 128;
    int K = a.K[z];
    if (k0 >= K) return;
    tp_tile(a.s[z], a.d[z], K, n0, k0, t, smem);
  } else {
    int row = bx - 2240;            // 0..339 = b*85 + l
    int b = row / 85, l = row % 85;
    const float* s = enc + (size_t)row * N_DC;
    u16* d;
    if (l < 77)      d = txt + (size_t)(b * 77 + l) * N_DC;
    else if (l < 81) d = img + (size_t)(b * 4 + (l - 77)) * N_DC;
    else             d = lbl + (size_t)(b * 4 + (l - 81)) * N_DC;
    for (int i = t * 8; i < N_DC; i += 256 * 8) {
      const float4 v0 = *(const float4*)(s + i);
      const float4 v1 = *(const float4*)(s + i + 4);
      alignas(16) u16 tmp[8];
      tmp[0] = f2b(v0.x); tmp[1] = f2b(v0.y); tmp[2] = f2b(v0.z); tmp[3] = f2b(v0.w);
      tmp[4] = f2b(v1.x); tmp[5] = f2b(v1.y); tmp[6] = f2b(v1.z); tmp[7] = f2b(v1.w);
      *(uint4*)(d + i) = *(uint4*)tmp;
    }
  }
}

// ---------- prep B: hs f32 -> bf16, lane-dense
__global__ __launch_bounds__(256)
void k_cvt(const float* __restrict__ src, u16* __restrict__ dst, int n4) {
  for (int i = blockIdx.x * 256 + threadIdx.x; i < n4; i += 2048 * 256) {
    float4 v = ((const float4*)src)[i];
    union { u16 s[4]; uint2 u; } tmp;
    tmp.s[0] = f2b(v.x); tmp.s[1] = f2b(v.y);
    tmp.s[2] = f2b(v.z); tmp.s[3] = f2b(v.w);
    ((uint2*)dst)[i] = tmp.u;
  }
}

// ====== 128x160 GEMM body (r11/r15: straight-line dbuf, 2 blk/CU) ==========
__device__ __forceinline__ void stage32(const u16* __restrict__ g, int ldK,
                                        int row0, int kk, u16* ldsb,
                                        int w, int lane) {
  int r = row0 + w * 8 + (lane >> 3);
  int gslot = ((lane & 7) ^ (lane >> 3)) << 3;
  gld16(g + (size_t)r * ldK + kk + gslot, ldsb + w * 512);
}
__device__ __forceinline__ void stageA(const u16* Ag, int K, int kk, u16* ldsb,
                                       int w, int lane) {
#pragma unroll
  for (int j = 0; j < 4; j++)
    stage32(Ag, K, j * 32, kk, ldsb + j * 2048, w, lane);
}
__device__ __forceinline__ void stageB(const u16* Bg, int K, int kk, u16* ldsb,
                                       int w, int lane) {
#pragma unroll
  for (int j = 0; j < 5; j++)
    stage32(Bg, K, j * 32, kk, ldsb + j * 2048, w, lane);
}

#define RD_A2(aoff, mh)                                                      \
  _Pragma("unroll") for (int mi = 0; mi < 2; mi++) {                         \
    _Pragma("unroll") for (int ks = 0; ks < 2; ks++) {                       \
      int row = wr * 64 + ((mh) * 2 + mi) * 16 + lrow;                       \
      int slot = (ks * 4 + g) ^ (lane & 7);                                  \
      af[mi][ks] = *(const bf16x8*)&lds[(aoff) + row * 64 + slot * 8];       \
    }                                                                        \
  }

#define RD_B5(boff)                                                          \
  _Pragma("unroll") for (int n = 0; n < 5; n++) {                            \
    _Pragma("unroll") for (int ks = 0; ks < 2; ks++) {                       \
      int row = wc * 80 + n * 16 + lrow;                                     \
      int slot = (ks * 4 + g) ^ (lane & 7);                                  \
      bf[n][ks] = *(const bf16x8*)&lds[(boff) + row * 64 + slot * 8];        \
    }                                                                        \
  }

#define MFMA10(mh)                                                           \
  _Pragma("unroll") for (int ks = 0; ks < 2; ks++) {                         \
    _Pragma("unroll") for (int n = 0; n < 5; n++)                            \
      acc[mh][n] = __builtin_amdgcn_mfma_f32_16x16x32_bf16(                  \
          af[(mh) & 1][ks], bf[n][ks], acc[mh][n], 0, 0, 0);                 \
  }

#define BARR()  __builtin_amdgcn_s_barrier()
#define VM0()   asm volatile("s_waitcnt vmcnt(0)" ::: "memory")
#define PRIO(x) __builtin_amdgcn_s_setprio(x)

template<int EPI>
__device__ __forceinline__ void gemm_body(
    const u16* __restrict__ A, const u16* __restrict__ Bt, void* __restrict__ Cv,
    int M, int N, int K, float scale,
    const float* __restrict__ bias, const float* __restrict__ resid,
    u16* lds, int bid, int nwg) {
  const int t = threadIdx.x, lane = t & 63, w = t >> 6;   // w in 0..3
  const int wr = w >> 1, wc = w & 1;
  const int lrow = lane & 15, g = lane >> 4;

  int nt = N / 160;
  int swz = ((nwg & 7) == 0) ? ((bid & 7) * (nwg >> 3) + (bid >> 3)) : bid;
  int bm = swz / nt, bn = swz % nt;

  const u16* Ag = A  + (size_t)bm * 128 * K;
  const u16* Bg = Bt + (size_t)bn * 160 * K;
  const int NT = K >> 6;

  f32x4 acc[4][5] = {};
  bf16x8 af[2][2], bf[5][2];

  stageA(Ag, K, 0, lds + 0,     w, lane);
  stageB(Bg, K, 0, lds + 16384, w, lane);
  VM0();
  BARR();

  for (int tt = 0; tt < NT; ++tt) {
    int c = tt & 1;
    int aof  = c * 8192,        bof  = 16384 + c * 10240;
    int aof1 = (c ^ 1) * 8192,  bof1 = 16384 + (c ^ 1) * 10240;
    if (tt + 1 < NT) {
      stageA(Ag, K, (tt + 1) * 64, lds + aof1, w, lane);
      stageB(Bg, K, (tt + 1) * 64, lds + bof1, w, lane);
    }
    RD_B5(bof);
    RD_A2(aof, 0);
    PRIO(1); MFMA10(0); MFMA10(1); PRIO(0);
    RD_A2(aof, 1);
    PRIO(1); MFMA10(2); MFMA10(3); PRIO(0);
    VM0();
    BARR();
  }

#pragma unroll
  for (int m = 0; m < 4; m++) {
    int row = bm * 128 + wr * 64 + m * 16 + g * 4;
#pragma unroll
    for (int n = 0; n < 5; n++) {
      int col = bn * 160 + wc * 80 + n * 16 + lrow;
#pragma unroll
      for (int j = 0; j < 4; j++) {
        float v = acc[m][n][j];
        if constexpr (EPI == 1)
          ((u16*)Cv)[(size_t)(row + j) * N + col] = f2b(v * scale);
        else
          ((float*)Cv)[(size_t)(row + j) * N + col] =
              v + bias[col] + resid[(size_t)(row + j) * N + col];
      }
    }
  }
}

// ---------- kv-projection body (XOR slot swizzle, conflict-free)
__device__ __forceinline__ void kv_body(
    const u16* __restrict__ A, const u16* __restrict__ Bt, u16* __restrict__ C,
    int M, int bm, int bn, u16* ldsraw) {
  u16 (*lds)[2][8192] = (u16(*)[2][8192])ldsraw;
  const int K = 2048;
  int t = threadIdx.x, lane = t & 63, w = t >> 6;
  int wm = w >> 1, wn = w & 1;
  int gs = ((lane & 7) ^ (lane >> 3)) * 8;
  int rsub = lane >> 3;

  f32x4 acc[4][4] = {};

#define KVSTAGE(kt, buf)                                                      \
  {                                                                           \
    int k0 = (kt) * 64;                                                       \
    _Pragma("unroll") for (int i2 = 0; i2 < 4; i2++) {                        \
      int rloc = w * 32 + i2 * 8;                                             \
      int ra = bm * 128 + rloc + rsub; if (ra >= M) ra = M - 1;               \
      int rb = bn * 128 + rloc + rsub;                                        \
      gld16(A  + (size_t)ra * K + k0 + gs, &lds[buf][0][rloc * 64]);          \
      gld16(Bt + (size_t)rb * K + k0 + gs, &lds[buf][1][rloc * 64]);          \
    }                                                                         \
  }

  KVSTAGE(0, 0);
  VM0();
  __syncthreads();
  int cur = 0;
  for (int kt = 0; kt < 32; kt++) {
    if (kt < 31) KVSTAGE(kt + 1, cur ^ 1);
#pragma unroll
    for (int ks = 0; ks < 2; ks++) {
      bf16x8 afr[4], bfr[4];
#pragma unroll
      for (int m = 0; m < 4; m++) {
        int row = wm * 64 + m * 16 + (lane & 15);
        int slot = (ks * 4 + (lane >> 4)) ^ (lane & 7);
        afr[m] = *(bf16x8*)&lds[cur][0][row * 64 + slot * 8];
      }
#pragma unroll
      for (int n = 0; n < 4; n++) {
        int row = wn * 64 + n * 16 + (lane & 15);
        int slot = (ks * 4 + (lane >> 4)) ^ (lane & 7);
        bfr[n] = *(bf16x8*)&lds[cur][1][row * 64 + slot * 8];
      }
#pragma unroll
      for (int m = 0; m < 4; m++)
#pragma unroll
        for (int n = 0; n < 4; n++)
          acc[m][n] = __builtin_amdgcn_mfma_f32_16x16x32_bf16(afr[m], bfr[n], acc[m][n], 0, 0, 0);
    }
    VM0();
    __syncthreads();
    cur ^= 1;
  }
#undef KVSTAGE

#pragma unroll
  for (int m = 0; m < 4; m++) {
    int row = bm * 128 + wm * 64 + m * 16 + ((lane >> 4) << 2);
#pragma unroll
    for (int n = 0; n < 4; n++) {
      int col = bn * 128 + wn * 64 + n * 16 + (lane & 15);
#pragma unroll
      for (int j = 0; j < 4; j++) {
        int r = row + j;
        if (r >= M) continue;
        C[(size_t)r * 1280 + col] = f2b(acc[m][n][j]);
      }
    }
  }
}

// ---------- combined: 100 KV blocks FIRST, then 1024 Q blocks
__global__ __launch_bounds__(256, 2)
void qkv_gemm(const u16* __restrict__ hsb, const u16* __restrict__ wq,
              u16* __restrict__ qbuf,
              const u16* __restrict__ etxt, const u16* __restrict__ eimg,
              const u16* __restrict__ elbl,
              const u16* __restrict__ wk,   const u16* __restrict__ wv,
              const u16* __restrict__ wkip, const u16* __restrict__ wvip,
              const u16* __restrict__ wklb, const u16* __restrict__ wvlb,
              u16* ktxt, u16* vtxt, u16* kimg, u16* vimg, u16* klbl, u16* vlbl) {
  __shared__ __align__(16) u16 lds[36864];   // 72 KB
  int bx = blockIdx.x;
  if (bx < 100) {
    int bn = bx % 10, my = (bx / 10) % 5, kv = bx / 50;
    const u16 *A, *Bt; u16* C; int M, bm;
    if (my < 3)       { A = etxt; M = 308; bm = my; Bt = kv ? wv   : wk;   C = kv ? vtxt : ktxt; }
    else if (my == 3) { A = eimg; M = 16;  bm = 0;  Bt = kv ? wvip : wkip; C = kv ? vimg : kimg; }
    else              { A = elbl; M = 16;  bm = 0;  Bt = kv ? wvlb : wklb; C = kv ? vlbl : klbl; }
    kv_body(A, Bt, C, M, bm, bn, lds);
  } else {
    gemm_body<1>(hsb, wq, qbuf, 16384, 1280, 1280, 0.125f, nullptr, nullptr,
                 lds, bx - 100, 1024);
  }
}

// ---------- O-proj wrapper
__global__ __launch_bounds__(256, 2)
void gemm_o(const u16* __restrict__ A, const u16* __restrict__ Bt,
            float* __restrict__ Cv, const float* __restrict__ bias,
            const float* __restrict__ resid) {
  __shared__ __align__(16) u16 lds[36864];
  gemm_body<2>(A, Bt, Cv, 16384, 1280, 1280, 1.f, bias, resid,
               lds, blockIdx.x, 1024);
}

// ---------- fused attention (Q direct->reg, 39.9KB LDS, 4 blk/CU) +
// Wo transpose (blocks 2560..2759)
#define QSTR 72
#define PSTR 104
// LDS layout (bytes): Ks [0,13824) 96x72 bf16 ; Vt [26624,39936) 64x104 ;
// Ps [0,26624) 128x104 (overlaps Ks AFTER the post-QK barrier).

__global__ __launch_bounds__(256, 4)
void attn_kern(const u16* __restrict__ q,
               const u16* __restrict__ ktxt, const u16* __restrict__ vtxt,
               const u16* __restrict__ kimg, const u16* __restrict__ vimg,
               const u16* __restrict__ klbl, const u16* __restrict__ vlbl,
               u16* __restrict__ outa,
               const float* __restrict__ Wo, u16* __restrict__ wo_t) {
  __shared__ __align__(16) char smem[39936];
  int bx = blockIdx.x;
  int t = threadIdx.x;
  if (bx >= 2560) {
    int v = bx - 2560;              // 0..199
    int n0 = (v % 20) * 64, k0 = (v / 20) * 128;
    tp_tile(Wo, wo_t, 1280, n0, k0, t, smem);
    return;
  }
  u16* Ks = (u16*)smem;
  u16* Ps = (u16*)smem;
  u16* Vt = (u16*)(smem + 26624);

  int st = bx & 31, h = (bx >> 5) % 20, b = bx / 640;
  int lane = t & 63, w = t >> 6;
  int s0 = st * 128;
  int c = lane & 15, g = lane >> 4;

  // Q fragments direct global->reg (issued first; latency hides under staging)
  bf16x8 aq[2][2];
#pragma unroll
  for (int m = 0; m < 2; m++)
#pragma unroll
    for (int ks = 0; ks < 2; ks++)
      aq[m][ks] = *(const bf16x8*)(q +
          (size_t)(b * N_S + s0 + w * 32 + m * 16 + c) * N_C + h * N_D +
          ks * 32 + g * 8);

  // zero Ks + Vt
  for (int i = t; i < 39936 / 16; i += 256)
    ((uint4*)smem)[i] = make_uint4(0, 0, 0, 0);
  __syncthreads();
  // stage K rows (slots: text 0..76, img 80..83, lbl 84..87)
  for (int cid = t; cid < 680; cid += 256) {
    int l = cid >> 3, c8 = cid & 7;
    const u16* p;
    if (l < 77)      p = ktxt + (size_t)(b * 77 + l) * N_C + h * N_D + c8 * 8;
    else if (l < 81) p = kimg + (size_t)(b * 4 + l - 77) * N_C + h * N_D + c8 * 8;
    else             p = klbl + (size_t)(b * 4 + l - 81) * N_C + h * N_D + c8 * 8;
    int row = (l < 77) ? l : l + 3;
    *(uint4*)&Ks[row * QSTR + c8 * 8] = *(const uint4*)p;
  }
  // stage V transposed: Vt[d][slot]
  for (int e = t; e < 85 * 64; e += 256) {
    int l = e >> 6, d = e & 63;
    const u16* p;
    if (l < 77)      p = vtxt + (size_t)(b * 77 + l) * N_C + h * N_D + d;
    else if (l < 81) p = vimg + (size_t)(b * 4 + l - 77) * N_C + h * N_D + d;
    else             p = vlbl + (size_t)(b * 4 + l - 81) * N_C + h * N_D + d;
    int slot = (l < 77) ? l : l + 3;
    Vt[d * PSTR + slot] = *p;
  }
  __syncthreads();

  // QK^T: A fragment from registers, B (K) from LDS
  f32x4 sacc[2][6] = {};
#pragma unroll
  for (int ks = 0; ks < 2; ks++) {
    bf16x8 bk[6];
#pragma unroll
    for (int n = 0; n < 6; n++)
      bk[n] = *(bf16x8*)&Ks[(n * 16 + c) * QSTR + ks * 32 + g * 8];
#pragma unroll
    for (int m = 0; m < 2; m++)
#pragma unroll
      for (int n = 0; n < 6; n++)
        sacc[m][n] = __builtin_amdgcn_mfma_f32_16x16x32_bf16(aq[m][ks], bk[n], sacc[m][n], 0, 0, 0);
  }
  __syncthreads();   // all reads of Ks done; Ps may overwrite

  const float NEG = -1e30f;
#pragma unroll
  for (int m = 0; m < 2; m++) {
#pragma unroll
    for (int j = 0; j < 4; j++) {
      // text segment: full 16-lane reduce
      float tmax = NEG;
#pragma unroll
      for (int n = 0; n < 5; n++)
        if (n * 16 + c < 77) tmax = fmaxf(tmax, sacc[m][n][j]);
#pragma unroll
      for (int off = 1; off < 16; off <<= 1) tmax = fmaxf(tmax, __shfl_xor(tmax, off));
      float pv[5], tsum = 0.f;
#pragma unroll
      for (int n = 0; n < 5; n++) {
        float v = (n * 16 + c < 77) ? __expf(sacc[m][n][j] - tmax) : 0.f;
        pv[n] = v; tsum += v;
      }
#pragma unroll
      for (int off = 1; off < 16; off <<= 1) tsum += __shfl_xor(tsum, off);
      // img (c<4) + lbl (4<=c<8): both live in 4-lane groups -> one 2-step
      // shared reduction computes each group's max/sum
      float v5 = sacc[m][5][j];
      float smax = (c < 8) ? v5 : NEG;
      smax = fmaxf(smax, __shfl_xor(smax, 1));
      smax = fmaxf(smax, __shfl_xor(smax, 2));
      float se = (c < 8) ? __expf(v5 - smax) : 0.f;
      float ssum = se;
      ssum += __shfl_xor(ssum, 1);
      ssum += __shfl_xor(ssum, 2);
      float rt = 1.f / tsum;
      float p5 = (c < 8) ? se / ssum : 0.f;
      int rowl = w * 32 + m * 16 + g * 4 + j;
#pragma unroll
      for (int n = 0; n < 5; n++)
        Ps[rowl * PSTR + n * 16 + c] = f2b(pv[n] * rt);
      Ps[rowl * PSTR + 80 + c] = f2b(p5);
    }
  }
  __syncthreads();

  f32x4 oacc[2][4] = {};
#pragma unroll
  for (int ks = 0; ks < 3; ks++) {
    bf16x8 ap[2], bv[4];
#pragma unroll
    for (int m = 0; m < 2; m++)
      ap[m] = *(bf16x8*)&Ps[(w * 32 + m * 16 + c) * PSTR + ks * 32 + g * 8];
#pragma unroll
    for (int n = 0; n < 4; n++)
      bv[n] = *(bf16x8*)&Vt[(n * 16 + c) * PSTR + ks * 32 + g * 8];
#pragma unroll
    for (int m = 0; m < 2; m++)
#pragma unroll
      for (int n = 0; n < 4; n++)
        oacc[m][n] = __builtin_amdgcn_mfma_f32_16x16x32_bf16(ap[m], bv[n], oacc[m][n], 0, 0, 0);
  }

#pragma unroll
  for (int m = 0; m < 2; m++) {
    int rbase = w * 32 + m * 16 + g * 4;
#pragma unroll
    for (int n = 0; n < 4; n++) {
      int d = n * 16 + c;
#pragma unroll
      for (int j = 0; j < 4; j++) {
        int s = s0 + rbase + j;
        outa[(size_t)(b * N_S + s) * N_C + h * N_D + d] = f2b(oacc[m][n][j]);
      }
    }
  }
}

extern "C" void kernel_launch(void* const* d_in, const int* in_sizes, int n_in,
                              void* d_out, int out_size, void* d_ws, size_t ws_size,
                              hipStream_t stream) {
  const float* hs   = (const float*)d_in[0];
  const float* enc  = (const float*)d_in[1];
  const float* Wq   = (const float*)d_in[2];
  const float* Wk   = (const float*)d_in[3];
  const float* Wv   = (const float*)d_in[4];
  const float* Wkip = (const float*)d_in[5];
  const float* Wvip = (const float*)d_in[6];
  const float* Wklb = (const float*)d_in[7];
  const float* Wvlb = (const float*)d_in[8];
  const float* Wo   = (const float*)d_in[9];
  const float* bo   = (const float*)d_in[10];

  if (ws_size < 83087360u) return;
  char* ws = (char*)d_ws;
  u16* wq_t   = (u16*)(ws + 0);
  u16* wo_t   = (u16*)(ws + 3276800);
  u16* wk_t   = (u16*)(ws + 6553600);
  u16* wv_t   = (u16*)(ws + 11796480);
  u16* wkip_t = (u16*)(ws + 17039360);
  u16* wvip_t = (u16*)(ws + 22282240);
  u16* wklb_t = (u16*)(ws + 27525120);
  u16* wvlb_t = (u16*)(ws + 32768000);
  u16* etxt   = (u16*)(ws + 38010880);
  u16* eimg   = (u16*)(ws + 39272448);
  u16* elbl   = (u16*)(ws + 39337984);
  u16* ktxt   = (u16*)(ws + 39403520);
  u16* vtxt   = (u16*)(ws + 40192000);
  u16* kimg   = (u16*)(ws + 40980480);
  u16* vimg   = (u16*)(ws + 41021440);
  u16* klbl   = (u16*)(ws + 41062400);
  u16* vlbl   = (u16*)(ws + 41103360);
  u16* attn   = (u16*)(ws + 41144320);
  // d_out (84 MB): lower half = q bf16, upper half = hs bf16; both consumed
  // before the final O-proj overwrites d_out with f32 output.
  u16* qbuf   = (u16*)d_out;
  u16* hsb    = (u16*)d_out + (size_t)N_S * N_B * N_C;

  TPargs tp;   // 7 weights in k_prep; Wo handled inside attn launch
  tp.s[0] = Wq;   tp.d[0] = wq_t;   tp.K[0] = 1280;
  tp.s[1] = Wk;   tp.d[1] = wk_t;   tp.K[1] = 2048;
  tp.s[2] = Wv;   tp.d[2] = wv_t;   tp.K[2] = 2048;
  tp.s[3] = Wkip; tp.d[3] = wkip_t; tp.K[3] = 2048;
  tp.s[4] = Wvip; tp.d[4] = wvip_t; tp.K[4] = 2048;
  tp.s[5] = Wklb; tp.d[5] = wklb_t; tp.K[5] = 2048;
  tp.s[6] = Wvlb; tp.d[6] = wvlb_t; tp.K[6] = 2048;
  tp.s[7] = Wo;   tp.d[7] = wo_t;   tp.K[7] = 1280;   // unused in k_prep

  // prep A: transposes + encoder pack
  k_prep<<<2580, 256, 0, stream>>>(tp, enc, etxt, eimg, elbl);
  // prep B: hs->bf16 LAST so hsb is L3-warm for qkv_gemm
  k_cvt<<<2048, 256, 0, stream>>>(hs, hsb, (N_B * N_S * N_C) / 4);

  // KV blocks first, then 1024 Q-proj blocks
  qkv_gemm<<<1124, 256, 0, stream>>>(hsb, wq_t, qbuf,
                                     etxt, eimg, elbl,
                                     wk_t, wv_t, wkip_t, wvip_t, wklb_t, wvlb_t,
                                     ktxt, vtxt, kimg, vimg, klbl, vlbl);

  // attention (2560 blocks, 4 blk/CU) + Wo transpose (200 blocks)
  attn_kern<<<2760, 256, 0, stream>>>(qbuf, ktxt, vtxt, kimg, vimg,
                                      klbl, vlbl, attn, Wo, wo_t);

  // out = attn @ Wo + bo + hs
  gemm_o<<<1024, 256, 0, stream>>>(attn, wo_t, (float*)d_out, bo, hs);
}

// Round 22
// 207.730 us; speedup vs baseline: 1.0699x; 1.0041x over previous
//
#include <hip/hip_runtime.h>
#include <hip/hip_bf16.h>

typedef unsigned short u16;
using f32x4  = __attribute__((ext_vector_type(4))) float;
using bf16x8 = __attribute__((ext_vector_type(8))) short;

#define N_B 4
#define N_S 4096
#define N_C 1280
#define N_DC 2048
#define N_H 20
#define N_D 64

__device__ __forceinline__ u16 f2b(float f) {
  union { float f; unsigned u; } x; x.f = f;
  return (u16)((x.u + 0x7fffu + ((x.u >> 16) & 1u)) >> 16);
}

__device__ __forceinline__ void gld16(const u16* g, u16* l) {
  __builtin_amdgcn_global_load_lds(
      (const __attribute__((address_space(1))) unsigned int*)(g),
      (__attribute__((address_space(3))) unsigned int*)(l), 16, 0, 0);
}

struct TPargs { const float* s[8]; u16* d[8]; int K[8]; };

// 64n x 128k vectorized transpose tile: src f32 (K x N_C) -> dst bf16 (N x K)
__device__ __forceinline__ void tp_tile(const float* __restrict__ src,
                                        u16* __restrict__ dst, int K,
                                        int n0, int k0, int t, char* smem) {
  float (*tl)[65] = (float(*)[65])smem;   // [128][65] = 33280 B
  int r = t >> 4, c4 = (t & 15) * 4;
#pragma unroll
  for (int j = 0; j < 8; j++) {
    float4 v4 = *(const float4*)(src + (size_t)(k0 + j * 16 + r) * N_C + n0 + c4);
    tl[j * 16 + r][c4]     = v4.x;
    tl[j * 16 + r][c4 + 1] = v4.y;
    tl[j * 16 + r][c4 + 2] = v4.z;
    tl[j * 16 + r][c4 + 3] = v4.w;
  }
  __syncthreads();
  int n = t >> 4, koff = (t & 15) * 8;
#pragma unroll
  for (int j = 0; j < 4; j++) {
    int nn = j * 16 + n;
    alignas(16) u16 tmp[8];
#pragma unroll
    for (int kk = 0; kk < 8; kk++) tmp[kk] = f2b(tl[koff + kk][nn]);
    *(uint4*)(dst + (size_t)(n0 + nn) * K + k0 + koff) = *(uint4*)tmp;
  }
}

// ---------- prep A: encoder pack FIRST (tail-fill), then 7 weight transposes
// blocks [0,340): encpack; [340,2580): transpose
__global__ __launch_bounds__(256)
void k_prep(TPargs a, const float* __restrict__ enc, u16* __restrict__ txt,
            u16* __restrict__ img, u16* __restrict__ lbl) {
  __shared__ __align__(16) char smem[33280];
  int bx = blockIdx.x, t = threadIdx.x;
  if (bx < 340) {
    int row = bx;                   // 0..339 = b*85 + l
    int b = row / 85, l = row % 85;
    const float* s = enc + (size_t)row * N_DC;
    u16* d;
    if (l < 77)      d = txt + (size_t)(b * 77 + l) * N_DC;
    else if (l < 81) d = img + (size_t)(b * 4 + (l - 77)) * N_DC;
    else             d = lbl + (size_t)(b * 4 + (l - 81)) * N_DC;
    for (int i = t * 8; i < N_DC; i += 256 * 8) {
      const float4 v0 = *(const float4*)(s + i);
      const float4 v1 = *(const float4*)(s + i + 4);
      alignas(16) u16 tmp[8];
      tmp[0] = f2b(v0.x); tmp[1] = f2b(v0.y); tmp[2] = f2b(v0.z); tmp[3] = f2b(v0.w);
      tmp[4] = f2b(v1.x); tmp[5] = f2b(v1.y); tmp[6] = f2b(v1.z); tmp[7] = f2b(v1.w);
      *(uint4*)(d + i) = *(uint4*)tmp;
    }
  } else {
    int z = (bx - 340) / 320, v = (bx - 340) % 320;
    int n0 = (v % 20) * 64, k0 = (v / 20) * 128;
    int K = a.K[z];
    if (k0 >= K) return;
    tp_tile(a.s[z], a.d[z], K, n0, k0, t, smem);
  }
}

// ---------- prep B: hs f32 -> bf16, lane-dense
__global__ __launch_bounds__(256)
void k_cvt(const float* __restrict__ src, u16* __restrict__ dst, int n4) {
  for (int i = blockIdx.x * 256 + threadIdx.x; i < n4; i += 2048 * 256) {
    float4 v = ((const float4*)src)[i];
    union { u16 s[4]; uint2 u; } tmp;
    tmp.s[0] = f2b(v.x); tmp.s[1] = f2b(v.y);
    tmp.s[2] = f2b(v.z); tmp.s[3] = f2b(v.w);
    ((uint2*)dst)[i] = tmp.u;
  }
}

// ====== 128x160 GEMM body (r11/r15: straight-line dbuf, 2 blk/CU) ==========
__device__ __forceinline__ void stage32(const u16* __restrict__ g, int ldK,
                                        int row0, int kk, u16* ldsb,
                                        int w, int lane) {
  int r = row0 + w * 8 + (lane >> 3);
  int gslot = ((lane & 7) ^ (lane >> 3)) << 3;
  gld16(g + (size_t)r * ldK + kk + gslot, ldsb + w * 512);
}
__device__ __forceinline__ void stageA(const u16* Ag, int K, int kk, u16* ldsb,
                                       int w, int lane) {
#pragma unroll
  for (int j = 0; j < 4; j++)
    stage32(Ag, K, j * 32, kk, ldsb + j * 2048, w, lane);
}
__device__ __forceinline__ void stageB(const u16* Bg, int K, int kk, u16* ldsb,
                                       int w, int lane) {
#pragma unroll
  for (int j = 0; j < 5; j++)
    stage32(Bg, K, j * 32, kk, ldsb + j * 2048, w, lane);
}

#define RD_A2(aoff, mh)                                                      \
  _Pragma("unroll") for (int mi = 0; mi < 2; mi++) {                         \
    _Pragma("unroll") for (int ks = 0; ks < 2; ks++) {                       \
      int row = wr * 64 + ((mh) * 2 + mi) * 16 + lrow;                       \
      int slot = (ks * 4 + g) ^ (lane & 7);                                  \
      af[mi][ks] = *(const bf16x8*)&lds[(aoff) + row * 64 + slot * 8];       \
    }                                                                        \
  }

#define RD_B5(boff)                                                          \
  _Pragma("unroll") for (int n = 0; n < 5; n++) {                            \
    _Pragma("unroll") for (int ks = 0; ks < 2; ks++) {                       \
      int row = wc * 80 + n * 16 + lrow;                                     \
      int slot = (ks * 4 + g) ^ (lane & 7);                                  \
      bf[n][ks] = *(const bf16x8*)&lds[(boff) + row * 64 + slot * 8];        \
    }                                                                        \
  }

#define MFMA10(mh)                                                           \
  _Pragma("unroll") for (int ks = 0; ks < 2; ks++) {                         \
    _Pragma("unroll") for (int n = 0; n < 5; n++)                            \
      acc[mh][n] = __builtin_amdgcn_mfma_f32_16x16x32_bf16(                  \
          af[(mh) & 1][ks], bf[n][ks], acc[mh][n], 0, 0, 0);                 \
  }

#define BARR()  __builtin_amdgcn_s_barrier()
#define VM0()   asm volatile("s_waitcnt vmcnt(0)" ::: "memory")
#define PRIO(x) __builtin_amdgcn_s_setprio(x)

template<int EPI>
__device__ __forceinline__ void gemm_body(
    const u16* __restrict__ A, const u16* __restrict__ Bt, void* __restrict__ Cv,
    int M, int N, int K, float scale,
    const float* __restrict__ bias, const float* __restrict__ resid,
    u16* lds, int bid, int nwg) {
  const int t = threadIdx.x, lane = t & 63, w = t >> 6;   // w in 0..3
  const int wr = w >> 1, wc = w & 1;
  const int lrow = lane & 15, g = lane >> 4;

  int nt = N / 160;
  int swz = ((nwg & 7) == 0) ? ((bid & 7) * (nwg >> 3) + (bid >> 3)) : bid;
  int bm = swz / nt, bn = swz % nt;

  const u16* Ag = A  + (size_t)bm * 128 * K;
  const u16* Bg = Bt + (size_t)bn * 160 * K;
  const int NT = K >> 6;

  f32x4 acc[4][5] = {};
  bf16x8 af[2][2], bf[5][2];

  stageA(Ag, K, 0, lds + 0,     w, lane);
  stageB(Bg, K, 0, lds + 16384, w, lane);
  VM0();
  BARR();

  for (int tt = 0; tt < NT; ++tt) {
    int c = tt & 1;
    int aof  = c * 8192,        bof  = 16384 + c * 10240;
    int aof1 = (c ^ 1) * 8192,  bof1 = 16384 + (c ^ 1) * 10240;
    if (tt + 1 < NT) {
      stageA(Ag, K, (tt + 1) * 64, lds + aof1, w, lane);
      stageB(Bg, K, (tt + 1) * 64, lds + bof1, w, lane);
    }
    RD_B5(bof);
    RD_A2(aof, 0);
    PRIO(1); MFMA10(0); MFMA10(1); PRIO(0);
    RD_A2(aof, 1);
    PRIO(1); MFMA10(2); MFMA10(3); PRIO(0);
    VM0();
    BARR();
  }

#pragma unroll
  for (int m = 0; m < 4; m++) {
    int row = bm * 128 + wr * 64 + m * 16 + g * 4;
#pragma unroll
    for (int n = 0; n < 5; n++) {
      int col = bn * 160 + wc * 80 + n * 16 + lrow;
#pragma unroll
      for (int j = 0; j < 4; j++) {
        float v = acc[m][n][j];
        if constexpr (EPI == 1)
          ((u16*)Cv)[(size_t)(row + j) * N + col] = f2b(v * scale);
        else
          ((float*)Cv)[(size_t)(row + j) * N + col] =
              v + bias[col] + resid[(size_t)(row + j) * N + col];
      }
    }
  }
}

// ---------- kv-projection body (XOR slot swizzle, conflict-free)
__device__ __forceinline__ void kv_body(
    const u16* __restrict__ A, const u16* __restrict__ Bt, u16* __restrict__ C,
    int M, int bm, int bn, u16* ldsraw) {
  u16 (*lds)[2][8192] = (u16(*)[2][8192])ldsraw;
  const int K = 2048;
  int t = threadIdx.x, lane = t & 63, w = t >> 6;
  int wm = w >> 1, wn = w & 1;
  int gs = ((lane & 7) ^ (lane >> 3)) * 8;
  int rsub = lane >> 3;

  f32x4 acc[4][4] = {};

#define KVSTAGE(kt, buf)                                                      \
  {                                                                           \
    int k0 = (kt) * 64;                                                       \
    _Pragma("unroll") for (int i2 = 0; i2 < 4; i2++) {                        \
      int rloc = w * 32 + i2 * 8;                                             \
      int ra = bm * 128 + rloc + rsub; if (ra >= M) ra = M - 1;               \
      int rb = bn * 128 + rloc + rsub;                                        \
      gld16(A  + (size_t)ra * K + k0 + gs, &lds[buf][0][rloc * 64]);          \
      gld16(Bt + (size_t)rb * K + k0 + gs, &lds[buf][1][rloc * 64]);          \
    }                                                                         \
  }

  KVSTAGE(0, 0);
  VM0();
  __syncthreads();
  int cur = 0;
  for (int kt = 0; kt < 32; kt++) {
    if (kt < 31) KVSTAGE(kt + 1, cur ^ 1);
#pragma unroll
    for (int ks = 0; ks < 2; ks++) {
      bf16x8 afr[4], bfr[4];
#pragma unroll
      for (int m = 0; m < 4; m++) {
        int row = wm * 64 + m * 16 + (lane & 15);
        int slot = (ks * 4 + (lane >> 4)) ^ (lane & 7);
        afr[m] = *(bf16x8*)&lds[cur][0][row * 64 + slot * 8];
      }
#pragma unroll
      for (int n = 0; n < 4; n++) {
        int row = wn * 64 + n * 16 + (lane & 15);
        int slot = (ks * 4 + (lane >> 4)) ^ (lane & 7);
        bfr[n] = *(bf16x8*)&lds[cur][1][row * 64 + slot * 8];
      }
#pragma unroll
      for (int m = 0; m < 4; m++)
#pragma unroll
        for (int n = 0; n < 4; n++)
          acc[m][n] = __builtin_amdgcn_mfma_f32_16x16x32_bf16(afr[m], bfr[n], acc[m][n], 0, 0, 0);
    }
    VM0();
    __syncthreads();
    cur ^= 1;
  }
#undef KVSTAGE

#pragma unroll
  for (int m = 0; m < 4; m++) {
    int row = bm * 128 + wm * 64 + m * 16 + ((lane >> 4) << 2);
#pragma unroll
    for (int n = 0; n < 4; n++) {
      int col = bn * 128 + wn * 64 + n * 16 + (lane & 15);
#pragma unroll
      for (int j = 0; j < 4; j++) {
        int r = row + j;
        if (r >= M) continue;
        C[(size_t)r * 1280 + col] = f2b(acc[m][n][j]);
      }
    }
  }
}

// ---------- combined: 100 KV blocks FIRST, then 1024 Q blocks
__global__ __launch_bounds__(256, 2)
void qkv_gemm(const u16* __restrict__ hsb, const u16* __restrict__ wq,
              u16* __restrict__ qbuf,
              const u16* __restrict__ etxt, const u16* __restrict__ eimg,
              const u16* __restrict__ elbl,
              const u16* __restrict__ wk,   const u16* __restrict__ wv,
              const u16* __restrict__ wkip, const u16* __restrict__ wvip,
              const u16* __restrict__ wklb, const u16* __restrict__ wvlb,
              u16* ktxt, u16* vtxt, u16* kimg, u16* vimg, u16* klbl, u16* vlbl) {
  __shared__ __align__(16) u16 lds[36864];   // 72 KB
  int bx = blockIdx.x;
  if (bx < 100) {
    int bn = bx % 10, my = (bx / 10) % 5, kv = bx / 50;
    const u16 *A, *Bt; u16* C; int M, bm;
    if (my < 3)       { A = etxt; M = 308; bm = my; Bt = kv ? wv   : wk;   C = kv ? vtxt : ktxt; }
    else if (my == 3) { A = eimg; M = 16;  bm = 0;  Bt = kv ? wvip : wkip; C = kv ? vimg : kimg; }
    else              { A = elbl; M = 16;  bm = 0;  Bt = kv ? wvlb : wklb; C = kv ? vlbl : klbl; }
    kv_body(A, Bt, C, M, bm, bn, lds);
  } else {
    gemm_body<1>(hsb, wq, qbuf, 16384, 1280, 1280, 0.125f, nullptr, nullptr,
                 lds, bx - 100, 1024);
  }
}

// ---------- O-proj wrapper
__global__ __launch_bounds__(256, 2)
void gemm_o(const u16* __restrict__ A, const u16* __restrict__ Bt,
            float* __restrict__ Cv, const float* __restrict__ bias,
            const float* __restrict__ resid) {
  __shared__ __align__(16) u16 lds[36864];
  gemm_body<2>(A, Bt, Cv, 16384, 1280, 1280, 1.f, bias, resid,
               lds, blockIdx.x, 1024);
}

// ---------- Wo transpose FIRST (blocks 0..199), then fused attention
#define QSTR 72
#define PSTR 104
// LDS layout (bytes): Ks [0,13824) ; Vt [26624,39936) ; Ps [0,26624)
// (Ps overlaps Ks AFTER the post-QK barrier).

__global__ __launch_bounds__(256, 4)
void attn_kern(const u16* __restrict__ q,
               const u16* __restrict__ ktxt, const u16* __restrict__ vtxt,
               const u16* __restrict__ kimg, const u16* __restrict__ vimg,
               const u16* __restrict__ klbl, const u16* __restrict__ vlbl,
               u16* __restrict__ outa,
               const float* __restrict__ Wo, u16* __restrict__ wo_t) {
  __shared__ __align__(16) char smem[39936];
  int bx = blockIdx.x;
  int t = threadIdx.x;
  if (bx < 200) {
    // Wo transpose tiles first: backfill attn round 1 instead of tailing
    int n0 = (bx % 20) * 64, k0 = (bx / 20) * 128;
    tp_tile(Wo, wo_t, 1280, n0, k0, t, smem);
    return;
  }
  int ab = bx - 200;
  u16* Ks = (u16*)smem;
  u16* Ps = (u16*)smem;
  u16* Vt = (u16*)(smem + 26624);

  int st = ab & 31, h = (ab >> 5) % 20, b = ab / 640;
  int lane = t & 63, w = t >> 6;
  int s0 = st * 128;
  int c = lane & 15, g = lane >> 4;

  // Q fragments direct global->reg (issued first; latency hides under staging)
  bf16x8 aq[2][2];
#pragma unroll
  for (int m = 0; m < 2; m++)
#pragma unroll
    for (int ks = 0; ks < 2; ks++)
      aq[m][ks] = *(const bf16x8*)(q +
          (size_t)(b * N_S + s0 + w * 32 + m * 16 + c) * N_C + h * N_D +
          ks * 32 + g * 8);

  // zero Ks + Vt
  for (int i = t; i < 39936 / 16; i += 256)
    ((uint4*)smem)[i] = make_uint4(0, 0, 0, 0);
  __syncthreads();
  // stage K rows (slots: text 0..76, img 80..83, lbl 84..87)
  for (int cid = t; cid < 680; cid += 256) {
    int l = cid >> 3, c8 = cid & 7;
    const u16* p;
    if (l < 77)      p = ktxt + (size_t)(b * 77 + l) * N_C + h * N_D + c8 * 8;
    else if (l < 81) p = kimg + (size_t)(b * 4 + l - 77) * N_C + h * N_D + c8 * 8;
    else             p = klbl + (size_t)(b * 4 + l - 81) * N_C + h * N_D + c8 * 8;
    int row = (l < 77) ? l : l + 3;
    *(uint4*)&Ks[row * QSTR + c8 * 8] = *(const uint4*)p;
  }
  // stage V transposed: Vt[d][slot]
  for (int e = t; e < 85 * 64; e += 256) {
    int l = e >> 6, d = e & 63;
    const u16* p;
    if (l < 77)      p = vtxt + (size_t)(b * 77 + l) * N_C + h * N_D + d;
    else if (l < 81) p = vimg + (size_t)(b * 4 + l - 77) * N_C + h * N_D + d;
    else             p = vlbl + (size_t)(b * 4 + l - 81) * N_C + h * N_D + d;
    int slot = (l < 77) ? l : l + 3;
    Vt[d * PSTR + slot] = *p;
  }
  __syncthreads();

  // QK^T: A fragment from registers, B (K) from LDS
  f32x4 sacc[2][6] = {};
#pragma unroll
  for (int ks = 0; ks < 2; ks++) {
    bf16x8 bk[6];
#pragma unroll
    for (int n = 0; n < 6; n++)
      bk[n] = *(bf16x8*)&Ks[(n * 16 + c) * QSTR + ks * 32 + g * 8];
#pragma unroll
    for (int m = 0; m < 2; m++)
#pragma unroll
      for (int n = 0; n < 6; n++)
        sacc[m][n] = __builtin_amdgcn_mfma_f32_16x16x32_bf16(aq[m][ks], bk[n], sacc[m][n], 0, 0, 0);
  }
  __syncthreads();   // all reads of Ks done; Ps may overwrite

  const float NEG = -1e30f;
#pragma unroll
  for (int m = 0; m < 2; m++) {
#pragma unroll
    for (int j = 0; j < 4; j++) {
      float tmax = NEG;
#pragma unroll
      for (int n = 0; n < 5; n++)
        if (n * 16 + c < 77) tmax = fmaxf(tmax, sacc[m][n][j]);
#pragma unroll
      for (int off = 1; off < 16; off <<= 1) tmax = fmaxf(tmax, __shfl_xor(tmax, off));
      float pv[5], tsum = 0.f;
#pragma unroll
      for (int n = 0; n < 5; n++) {
        float v = (n * 16 + c < 77) ? __expf(sacc[m][n][j] - tmax) : 0.f;
        pv[n] = v; tsum += v;
      }
#pragma unroll
      for (int off = 1; off < 16; off <<= 1) tsum += __shfl_xor(tsum, off);
      float v5 = sacc[m][5][j];
      float smax = (c < 8) ? v5 : NEG;
      smax = fmaxf(smax, __shfl_xor(smax, 1));
      smax = fmaxf(smax, __shfl_xor(smax, 2));
      float se = (c < 8) ? __expf(v5 - smax) : 0.f;
      float ssum = se;
      ssum += __shfl_xor(ssum, 1);
      ssum += __shfl_xor(ssum, 2);
      float rt = 1.f / tsum;
      float p5 = (c < 8) ? se / ssum : 0.f;
      int rowl = w * 32 + m * 16 + g * 4 + j;
#pragma unroll
      for (int n = 0; n < 5; n++)
        Ps[rowl * PSTR + n * 16 + c] = f2b(pv[n] * rt);
      Ps[rowl * PSTR + 80 + c] = f2b(p5);
    }
  }
  __syncthreads();

  f32x4 oacc[2][4] = {};
#pragma unroll
  for (int ks = 0; ks < 3; ks++) {
    bf16x8 ap[2], bv[4];
#pragma unroll
    for (int m = 0; m < 2; m++)
      ap[m] = *(bf16x8*)&Ps[(w * 32 + m * 16 + c) * PSTR + ks * 32 + g * 8];
#pragma unroll
    for (int n = 0; n < 4; n++)
      bv[n] = *(bf16x8*)&Vt[(n * 16 + c) * PSTR + ks * 32 + g * 8];
#pragma unroll
    for (int m = 0; m < 2; m++)
#pragma unroll
      for (int n = 0; n < 4; n++)
        oacc[m][n] = __builtin_amdgcn_mfma_f32_16x16x32_bf16(ap[m], bv[n], oacc[m][n], 0, 0, 0);
  }

#pragma unroll
  for (int m = 0; m < 2; m++) {
    int rbase = w * 32 + m * 16 + g * 4;
#pragma unroll
    for (int n = 0; n < 4; n++) {
      int d = n * 16 + c;
#pragma unroll
      for (int j = 0; j < 4; j++) {
        int s = s0 + rbase + j;
        outa[(size_t)(b * N_S + s) * N_C + h * N_D + d] = f2b(oacc[m][n][j]);
      }
    }
  }
}

extern "C" void kernel_launch(void* const* d_in, const int* in_sizes, int n_in,
                              void* d_out, int out_size, void* d_ws, size_t ws_size,
                              hipStream_t stream) {
  const float* hs   = (const float*)d_in[0];
  const float* enc  = (const float*)d_in[1];
  const float* Wq   = (const float*)d_in[2];
  const float* Wk   = (const float*)d_in[3];
  const float* Wv   = (const float*)d_in[4];
  const float* Wkip = (const float*)d_in[5];
  const float* Wvip = (const float*)d_in[6];
  const float* Wklb = (const float*)d_in[7];
  const float* Wvlb = (const float*)d_in[8];
  const float* Wo   = (const float*)d_in[9];
  const float* bo   = (const float*)d_in[10];

  if (ws_size < 83087360u) return;
  char* ws = (char*)d_ws;
  u16* wq_t   = (u16*)(ws + 0);
  u16* wo_t   = (u16*)(ws + 3276800);
  u16* wk_t   = (u16*)(ws + 6553600);
  u16* wv_t   = (u16*)(ws + 11796480);
  u16* wkip_t = (u16*)(ws + 17039360);
  u16* wvip_t = (u16*)(ws + 22282240);
  u16* wklb_t = (u16*)(ws + 27525120);
  u16* wvlb_t = (u16*)(ws + 32768000);
  u16* etxt   = (u16*)(ws + 38010880);
  u16* eimg   = (u16*)(ws + 39272448);
  u16* elbl   = (u16*)(ws + 39337984);
  u16* ktxt   = (u16*)(ws + 39403520);
  u16* vtxt   = (u16*)(ws + 40192000);
  u16* kimg   = (u16*)(ws + 40980480);
  u16* vimg   = (u16*)(ws + 41021440);
  u16* klbl   = (u16*)(ws + 41062400);
  u16* vlbl   = (u16*)(ws + 41103360);
  u16* attn   = (u16*)(ws + 41144320);
  // d_out (84 MB): lower half = q bf16, upper half = hs bf16; both consumed
  // before the final O-proj overwrites d_out with f32 output.
  u16* qbuf   = (u16*)d_out;
  u16* hsb    = (u16*)d_out + (size_t)N_S * N_B * N_C;

  TPargs tp;   // 7 weights in k_prep; Wo handled inside attn launch
  tp.s[0] = Wq;   tp.d[0] = wq_t;   tp.K[0] = 1280;
  tp.s[1] = Wk;   tp.d[1] = wk_t;   tp.K[1] = 2048;
  tp.s[2] = Wv;   tp.d[2] = wv_t;   tp.K[2] = 2048;
  tp.s[3] = Wkip; tp.d[3] = wkip_t; tp.K[3] = 2048;
  tp.s[4] = Wvip; tp.d[4] = wvip_t; tp.K[4] = 2048;
  tp.s[5] = Wklb; tp.d[5] = wklb_t; tp.K[5] = 2048;
  tp.s[6] = Wvlb; tp.d[6] = wvlb_t; tp.K[6] = 2048;
  tp.s[7] = Wo;   tp.d[7] = wo_t;   tp.K[7] = 1280;   // unused in k_prep

  // prep A: encoder pack first (tail-fill), then transposes
  k_prep<<<2580, 256, 0, stream>>>(tp, enc, etxt, eimg, elbl);
  // prep B: hs->bf16 LAST so hsb is L3-warm for qkv_gemm
  k_cvt<<<2048, 256, 0, stream>>>(hs, hsb, (N_B * N_S * N_C) / 4);

  // KV blocks first, then 1024 Q-proj blocks
  qkv_gemm<<<1124, 256, 0, stream>>>(hsb, wq_t, qbuf,
                                     etxt, eimg, elbl,
                                     wk_t, wv_t, wkip_t, wvip_t, wklb_t, wvlb_t,
                                     ktxt, vtxt, kimg, vimg, klbl, vlbl);

  // Wo transpose (200 blocks, first) + attention (2560 blocks)
  attn_kern<<<2760, 256, 0, stream>>>(qbuf, ktxt, vtxt, kimg, vimg,
                                      klbl, vlbl, attn, Wo, wo_t);

  // out = attn @ Wo + bo + hs
  gemm_o<<<1024, 256, 0, stream>>>(attn, wo_t, (float*)d_out, bo, hs);
}